// Round 1
// baseline (6506.761 us; speedup 1.0000x reference)
//
#include <hip/hip_runtime.h>
#include <hip/hip_bf16.h>
#include <math.h>

// Problem constants (fixed by the reference)
#define NNODES 50000
#define NEDGES 800000
#define SDIM   128      // S
#define HDIM   256      // H
#define ECDIM  128      // EC
#define GIN    512      // 2*EC + 2*S
#define NROWS  9        // sum(DEG) = 1+3+5
#define NT     8        // nodes per block in node_k

__device__ __forceinline__ float silu(float x) {
    return x / (1.0f + __expf(-x));
}

// ---------------------------------------------------------------------------
// Scatter: c_sum[d] += t_ij[e], a_sum[d] += a_ij[e], cnt[d] += 1   (d = dst[e])
// 32 threads per edge, each owns a float4 (4 channels) of both t and a.
// ---------------------------------------------------------------------------
__global__ __launch_bounds__(256) void scatter_k(
    const float* __restrict__ t_ij, const float* __restrict__ a_ij,
    const int* __restrict__ dst,
    float* __restrict__ c_sum, float* __restrict__ a_sum, float* __restrict__ cnt)
{
    const long long total = (long long)NEDGES * 32;
    long long stride = (long long)gridDim.x * blockDim.x;
    for (long long i = (long long)blockIdx.x * blockDim.x + threadIdx.x;
         i < total; i += stride) {
        int e = (int)(i >> 5);
        int q = (int)(i & 31);
        int d = dst[e];
        float4 tv = ((const float4*)t_ij)[(size_t)e * 32 + q];
        float4 av = ((const float4*)a_ij)[(size_t)e * 32 + q];
        float* cb = c_sum + (size_t)d * ECDIM + q * 4;
        float* ab = a_sum + (size_t)d * ECDIM + q * 4;
        atomicAdd(cb + 0, tv.x); atomicAdd(cb + 1, tv.y);
        atomicAdd(cb + 2, tv.z); atomicAdd(cb + 3, tv.w);
        atomicAdd(ab + 0, av.x); atomicAdd(ab + 1, av.y);
        atomicAdd(ab + 2, av.z); atomicAdd(ab + 3, av.w);
        if (q == 0) atomicAdd(&cnt[d], 1.0f);
    }
}

// ---------------------------------------------------------------------------
// Per-node fused: norms -> gate MLP (x3 l) -> h rows -> gate -> @W2 -> out
// Block = 256 threads, NT=8 nodes. LDS 76 KB -> 2 blocks/CU.
// ---------------------------------------------------------------------------
__global__ __launch_bounds__(256, 2) void node_k(
    const float* __restrict__ x_emb,
    const float* __restrict__ c_sum, const float* __restrict__ a_sum,
    const float* __restrict__ cnt,
    const float* __restrict__ W1, const float* __restrict__ W2,
    const float* __restrict__ Wg1, const float* __restrict__ bg1,
    const float* __restrict__ Wg2, const float* __restrict__ bg2,
    float* __restrict__ out)
{
    __shared__ float xin[NT][NROWS][SDIM];  // 36 KB
    __shared__ float gin[NT][GIN];          // 16 KB: [c_i | c_ang | norm_l | x0]
    __shared__ float g1s[NT][HDIM];         //  8 KB
    __shared__ float g2s[NT][HDIM];         //  8 KB
    __shared__ float h8[NT][HDIM];          //  8 KB: one gated h-row per node

    const int t  = threadIdx.x;
    const int n0 = blockIdx.x * NT;

    // ---- load x_emb tile (8 nodes x 9 x 128 = 2304 float4) ----
    const float4* xsrc = (const float4*)(x_emb + (size_t)n0 * (NROWS * SDIM));
    float4* xdst = (float4*)xin;
    #pragma unroll
    for (int j = 0; j < 9; ++j) xdst[t + j * 256] = xsrc[t + j * 256];
    __syncthreads();

    // ---- gate_in shared parts: c_i, c_ang, x0 ----
    for (int idx = t; idx < NT * SDIM; idx += 256) {
        int n = idx >> 7, c = idx & 127;
        float ct  = cnt[n0 + n];
        float inv = 1.0f / fmaxf(ct, 1.0f);
        gin[n][c]           = c_sum[(size_t)(n0 + n) * ECDIM + c] * inv;
        gin[n][SDIM + c]    = a_sum[(size_t)(n0 + n) * ECDIM + c] * inv;
        gin[n][384 + c]     = xin[n][0][c];
    }
    __syncthreads();

    for (int l = 0; l < 3; ++l) {
        const int lo  = l * l;        // OFF[l] = 0,1,4
        const int deg = 2 * l + 1;

        // ---- norm_l into gin[.][256..383] ----
        for (int idx = t; idx < NT * SDIM; idx += 256) {
            int n = idx >> 7, c = idx & 127;
            float acc = 0.0f;
            for (int r = 0; r < deg; ++r) {
                float v = xin[n][lo + r][c];
                acc += v * v;
            }
            gin[n][256 + c] = sqrtf(acc);
        }
        __syncthreads();

        // ---- gate layer 1: g1 = silu(gin @ Wg1[l] + bg1[l]); thread = h col ----
        {
            float acc[NT];
            float b = bg1[l * HDIM + t];
            #pragma unroll
            for (int n = 0; n < NT; ++n) acc[n] = b;
            const float* w = Wg1 + (size_t)l * GIN * HDIM + t;
            for (int k = 0; k < GIN; k += 4) {
                float w0 = w[(k + 0) * HDIM], w1 = w[(k + 1) * HDIM];
                float w2v = w[(k + 2) * HDIM], w3 = w[(k + 3) * HDIM];
                #pragma unroll
                for (int n = 0; n < NT; ++n) {
                    float4 gv = *(const float4*)&gin[n][k];
                    acc[n] += gv.x * w0 + gv.y * w1 + gv.z * w2v + gv.w * w3;
                }
            }
            #pragma unroll
            for (int n = 0; n < NT; ++n) g1s[n][t] = silu(acc[n]);
        }
        __syncthreads();

        // ---- gate layer 2: g2 = silu(g1 @ Wg2[l] + bg2[l]) ----
        {
            float acc[NT];
            float b = bg2[l * HDIM + t];
            #pragma unroll
            for (int n = 0; n < NT; ++n) acc[n] = b;
            const float* w = Wg2 + (size_t)l * HDIM * HDIM + t;
            for (int k = 0; k < HDIM; k += 4) {
                float w0 = w[(k + 0) * HDIM], w1 = w[(k + 1) * HDIM];
                float w2v = w[(k + 2) * HDIM], w3 = w[(k + 3) * HDIM];
                #pragma unroll
                for (int n = 0; n < NT; ++n) {
                    float4 gv = *(const float4*)&g1s[n][k];
                    acc[n] += gv.x * w0 + gv.y * w1 + gv.z * w2v + gv.w * w3;
                }
            }
            #pragma unroll
            for (int n = 0; n < NT; ++n) g2s[n][t] = silu(acc[n]);
        }
        __syncthreads();

        // ---- per degree-row: h = x@W1, gate, out = gated @ W2 ----
        for (int c = 0; c < deg; ++c) {
            {   // h row (lo+c) for all 8 nodes; thread = h col
                float acc[NT];
                #pragma unroll
                for (int n = 0; n < NT; ++n) acc[n] = 0.0f;
                const float* w = W1 + t;
                for (int k = 0; k < SDIM; k += 4) {
                    float w0 = w[(k + 0) * HDIM], w1 = w[(k + 1) * HDIM];
                    float w2v = w[(k + 2) * HDIM], w3 = w[(k + 3) * HDIM];
                    #pragma unroll
                    for (int n = 0; n < NT; ++n) {
                        float4 xv = *(const float4*)&xin[n][lo + c][k];
                        acc[n] += xv.x * w0 + xv.y * w1 + xv.z * w2v + xv.w * w3;
                    }
                }
                #pragma unroll
                for (int n = 0; n < NT; ++n) {
                    float v = acc[n];
                    if (l == 0) v = silu(v);
                    h8[n][t] = v * g2s[n][t];
                }
            }
            __syncthreads();
            {   // out row = h8 @ W2 ; threads: s = t&127, half = t>>7 owns 4 nodes
                const int s    = t & 127;
                const int half = t >> 7;
                float acc[4] = {0.0f, 0.0f, 0.0f, 0.0f};
                const float* w = W2 + s;
                for (int k = 0; k < HDIM; k += 2) {
                    float w0 = w[k * SDIM], w1 = w[(k + 1) * SDIM];
                    #pragma unroll
                    for (int j = 0; j < 4; ++j) {
                        float2 hv = *(const float2*)&h8[half * 4 + j][k];
                        acc[j] += hv.x * w0 + hv.y * w1;
                    }
                }
                #pragma unroll
                for (int j = 0; j < 4; ++j) {
                    int n = half * 4 + j;
                    out[((size_t)(n0 + n) * NROWS + (lo + c)) * SDIM + s] = acc[j];
                }
            }
            __syncthreads();
        }
    }
}

extern "C" void kernel_launch(void* const* d_in, const int* in_sizes, int n_in,
                              void* d_out, int out_size, void* d_ws, size_t ws_size,
                              hipStream_t stream) {
    const float* x_emb = (const float*)d_in[0];
    const float* t_ij  = (const float*)d_in[1];
    const float* a_ij  = (const float*)d_in[2];
    const int*   eidx  = (const int*)d_in[3];   // (2, E) int32; row 1 = dst
    const float* W1  = (const float*)d_in[4];
    const float* W2  = (const float*)d_in[5];
    const float* Wg1 = (const float*)d_in[6];
    const float* bg1 = (const float*)d_in[7];
    const float* Wg2 = (const float*)d_in[8];
    const float* bg2 = (const float*)d_in[9];
    float* out = (float*)d_out;

    // workspace layout: c_sum (N*128) | a_sum (N*128) | cnt (N)   -- all f32
    float* c_sum = (float*)d_ws;
    float* a_sum = c_sum + (size_t)NNODES * ECDIM;
    float* cntb  = a_sum + (size_t)NNODES * ECDIM;
    size_t zero_bytes = ((size_t)2 * NNODES * ECDIM + NNODES) * sizeof(float);
    hipMemsetAsync(d_ws, 0, zero_bytes, stream);

    const int* dst = eidx + NEDGES;
    scatter_k<<<4096, 256, 0, stream>>>(t_ij, a_ij, dst, c_sum, a_sum, cntb);
    node_k<<<NNODES / NT, 256, 0, stream>>>(x_emb, c_sum, a_sum, cntb,
                                            W1, W2, Wg1, bg1, Wg2, bg2, out);
}

// Round 2
// 1409.714 us; speedup vs baseline: 4.6157x; 4.6157x over previous
//
#include <hip/hip_runtime.h>
#include <hip/hip_bf16.h>
#include <math.h>

// Problem constants
#define NNODES 50000
#define NEDGES 800000
#define SDIM   128
#define HDIM   256
#define ECDIM  128
#define NROWS  9
#define TOTROWS (NNODES * NROWS)   // 450000

typedef _Float16 f16;
typedef _Float16 f16x8 __attribute__((ext_vector_type(8)));
typedef float    f32x4 __attribute__((ext_vector_type(4)));

__device__ __forceinline__ float silu(float x) { return x / (1.0f + __expf(-x)); }

__device__ __forceinline__ f16x8 zero8() {
    f16x8 v;
    #pragma unroll
    for (int i = 0; i < 8; ++i) v[i] = (f16)0.0f;
    return v;
}

// ---------------------------------------------------------------------------
// Weight transpose + f16 convert. Dest layouts are [out_col][k] (K-contiguous).
// ---------------------------------------------------------------------------
__global__ __launch_bounds__(256) void wprep_k(
    const float* __restrict__ W1, const float* __restrict__ W2,
    const float* __restrict__ Wg1, const float* __restrict__ Wg2,
    f16* __restrict__ W1T, f16* __restrict__ W2T,
    f16* __restrict__ Wg1T, f16* __restrict__ Wg2T)
{
    int i = blockIdx.x * 256 + threadIdx.x;
    if (i < 32768) {  // W1T[n=256][k=128] = W1[k][n]
        int n = i >> 7, k = i & 127;
        W1T[i] = (f16)W1[k * 256 + n];
    }
    if (i < 32768) {  // W2T[s=128][k=256] = W2[k][s]
        int s = i >> 8, k = i & 255;
        W2T[i] = (f16)W2[k * 128 + s];
    }
    if (i < 393216) { // Wg1T[l][h=256][k=512] = Wg1[l][k][h]
        int l = i >> 17, r = i & 131071;
        int h = r >> 9, k = r & 511;
        Wg1T[i] = (f16)Wg1[l * 131072 + k * 256 + h];
    }
    if (i < 196608) { // Wg2T[l][h=256][k=256] = Wg2[l][k][h]
        int l = i >> 16, r = i & 65535;
        int h = r >> 8, k = r & 255;
        Wg2T[i] = (f16)Wg2[l * 65536 + k * 256 + h];
    }
}

// ---------------------------------------------------------------------------
// Per-node prep: x0 slot of gate base + norms for l=0,1,2 (f16).
// base layout per node: [c_i(128) | c_ang(128) | x0(128)]  (384 f16)
// ---------------------------------------------------------------------------
__global__ __launch_bounds__(256) void prep_k(
    const float* __restrict__ x, f16* __restrict__ base, f16* __restrict__ norms)
{
    int t = threadIdx.x;
    int node = blockIdx.x * 2 + (t >> 7);
    int c = t & 127;
    const float* xr = x + (size_t)node * (NROWS * SDIM) + c;
    float v0 = xr[0];
    float s1 = 0.0f, s2 = 0.0f;
    #pragma unroll
    for (int r = 1; r < 4; ++r) { float v = xr[r * 128]; s1 += v * v; }
    #pragma unroll
    for (int r = 4; r < 9; ++r) { float v = xr[r * 128]; s2 += v * v; }
    base[(size_t)node * 384 + 256 + c] = (f16)v0;
    norms[(size_t)node * 128 + c]                     = (f16)fabsf(v0);
    norms[((size_t)NNODES + node) * 128 + c]          = (f16)sqrtf(s1);
    norms[((size_t)2 * NNODES + node) * 128 + c]      = (f16)sqrtf(s2);
}

// ---------------------------------------------------------------------------
// CSR build
// ---------------------------------------------------------------------------
__global__ __launch_bounds__(256) void hist_k(const int* __restrict__ dst, int* __restrict__ cnt)
{
    int e = blockIdx.x * 256 + threadIdx.x;
    if (e < NEDGES) atomicAdd(&cnt[dst[e]], 1);
}

__global__ __launch_bounds__(1024) void scan_k(const int* __restrict__ cnt, int* __restrict__ row_start)
{
    __shared__ int part[1024];
    int t = threadIdx.x;
    int lo = t * 49, hi = min(lo + 49, NNODES);
    int s = 0;
    for (int i = lo; i < hi; ++i) s += cnt[i];
    part[t] = s;
    __syncthreads();
    for (int off = 1; off < 1024; off <<= 1) {
        int v = (t >= off) ? part[t - off] : 0;
        __syncthreads();
        part[t] += v;
        __syncthreads();
    }
    int run = part[t] - s;   // exclusive prefix of this chunk
    for (int i = lo; i < hi; ++i) { row_start[i] = run; run += cnt[i]; }
}

__global__ __launch_bounds__(256) void fill_k(
    const int* __restrict__ dst, const int* __restrict__ row_start,
    int* __restrict__ cur, int* __restrict__ eids)
{
    int e = blockIdx.x * 256 + threadIdx.x;
    if (e >= NEDGES) return;
    int d = dst[e];
    int p = atomicAdd(&cur[d], 1);
    eids[row_start[d] + p] = e;
}

// ---------------------------------------------------------------------------
// Gather means: wave per node; lane owns channels (2*ln, 2*ln+1) of c and a.
// Writes f16 means into base[node][0..256).
// ---------------------------------------------------------------------------
__global__ __launch_bounds__(256) void gather_k(
    const float* __restrict__ t_ij, const float* __restrict__ a_ij,
    const int* __restrict__ row_start, const int* __restrict__ cnt,
    const int* __restrict__ eids, f16* __restrict__ base)
{
    int wv = threadIdx.x >> 6, ln = threadIdx.x & 63;
    int node = blockIdx.x * 4 + wv;
    int rs = row_start[node];
    int n  = cnt[node];
    float cx = 0, cy = 0, ax = 0, ay = 0;
    int e = (n > 0) ? eids[rs] : 0;
    for (int i = 0; i < n; ++i) {
        int en = (i + 1 < n) ? eids[rs + i + 1] : 0;
        float2 tv = ((const float2*)t_ij)[(size_t)e * 64 + ln];
        float2 av = ((const float2*)a_ij)[(size_t)e * 64 + ln];
        cx += tv.x; cy += tv.y; ax += av.x; ay += av.y;
        e = en;
    }
    float inv = 1.0f / (float)(n > 0 ? n : 1);
    union { f16 h[2]; unsigned u; } pc, pa;
    pc.h[0] = (f16)(cx * inv); pc.h[1] = (f16)(cy * inv);
    pa.h[0] = (f16)(ax * inv); pa.h[1] = (f16)(ay * inv);
    unsigned* b32 = (unsigned*)base;
    b32[(size_t)node * 192 + ln]      = pc.u;   // c_i  elems [0,128)
    b32[(size_t)node * 192 + 64 + ln] = pa.u;   // c_ang elems [128,256)
}

// ---------------------------------------------------------------------------
// Gate MLP (both layers) for one l: g2 = silu(silu(gate_in@Wg1+b1)@Wg2+b2)
// Block: 64 nodes, 256 threads (4 waves), each wave 16 nodes x 256 cols.
// ---------------------------------------------------------------------------
__global__ __launch_bounds__(256, 2) void gate_k(
    const f16* __restrict__ base, const f16* __restrict__ norms,
    const f16* __restrict__ Wg1T, const f16* __restrict__ Wg2T,
    const float* __restrict__ bg1, const float* __restrict__ bg2,
    f16* __restrict__ g2out)
{
    const int l  = blockIdx.y;
    const int n0 = blockIdx.x * 64;
    const int t  = threadIdx.x;
    const int wv = t >> 6, ln = t & 63;
    const int col0 = ln & 15;   // also the within-wave A row
    const int kq   = ln >> 4;

    __shared__ f16 a_lds[64][40];     // 32-k tile, padded
    __shared__ f16 g1_lds[64][264];   // g1 (then reused for out staging)

    f32x4 acc[16];
    #pragma unroll
    for (int nt = 0; nt < 16; ++nt) {
        float b = bg1[l * 256 + nt * 16 + col0];
        f32x4 v = {b, b, b, b};
        acc[nt] = v;
    }

    const f16* wg1 = Wg1T + (size_t)l * 256 * 512;
    for (int ks = 0; ks < 16; ++ks) {
        int k0 = ks * 32;
        {   // stage A tile: 64 rows x 32 k
            int row = t >> 2, sg = t & 3;
            int node = n0 + row;
            f16x8 v = zero8();
            if (node < NNODES) {
                const f16* src;
                if (k0 < 256)      src = base  + (size_t)node * 384 + k0;
                else if (k0 < 384) src = norms + ((size_t)l * NNODES + node) * 128 + (k0 - 256);
                else               src = base  + (size_t)node * 384 + 256 + (k0 - 384);
                v = *(const f16x8*)(src + sg * 8);
            }
            *(f16x8*)&a_lds[row][sg * 8] = v;
        }
        __syncthreads();
        f16x8 a = *(const f16x8*)&a_lds[wv * 16 + col0][kq * 8];
        #pragma unroll
        for (int nt = 0; nt < 16; ++nt) {
            f16x8 b = *(const f16x8*)(wg1 + (size_t)(nt * 16 + col0) * 512 + k0 + kq * 8);
            acc[nt] = __builtin_amdgcn_mfma_f32_16x16x32_f16(a, b, acc[nt], 0, 0, 0);
        }
        __syncthreads();
    }

    // g1 = silu(acc) -> LDS (wave-local rows)
    #pragma unroll
    for (int nt = 0; nt < 16; ++nt)
        #pragma unroll
        for (int j = 0; j < 4; ++j) {
            int rl = wv * 16 + kq * 4 + j;
            g1_lds[rl][nt * 16 + col0] = (f16)silu(acc[nt][j]);
        }

    f32x4 acc2[16];
    #pragma unroll
    for (int nt = 0; nt < 16; ++nt) {
        float b = bg2[l * 256 + nt * 16 + col0];
        f32x4 v = {b, b, b, b};
        acc2[nt] = v;
    }
    const f16* wg2 = Wg2T + (size_t)l * 256 * 256;
    #pragma unroll
    for (int ks = 0; ks < 8; ++ks) {
        int k0 = ks * 32;
        f16x8 a = *(const f16x8*)&g1_lds[wv * 16 + col0][k0 + kq * 8];
        #pragma unroll
        for (int nt = 0; nt < 16; ++nt) {
            f16x8 b = *(const f16x8*)(wg2 + (size_t)(nt * 16 + col0) * 256 + k0 + kq * 8);
            acc2[nt] = __builtin_amdgcn_mfma_f32_16x16x32_f16(a, b, acc2[nt], 0, 0, 0);
        }
    }
    __syncthreads();
    // g2 = silu(acc2) -> LDS (reuse), then coalesced copy out
    #pragma unroll
    for (int nt = 0; nt < 16; ++nt)
        #pragma unroll
        for (int j = 0; j < 4; ++j) {
            int rl = wv * 16 + kq * 4 + j;
            g1_lds[rl][nt * 16 + col0] = (f16)silu(acc2[nt][j]);
        }
    __syncthreads();
    for (int it = 0; it < 8; ++it) {
        int idx = t + 256 * it;          // 2048 chunks of 8 f16
        int row = idx >> 5, sg = idx & 31;
        int node = n0 + row;
        if (node < NNODES) {
            f16x8 v = *(const f16x8*)&g1_lds[row][sg * 8];
            *(f16x8*)(g2out + ((size_t)l * NNODES + node) * 256 + sg * 8) = v;
        }
    }
}

// ---------------------------------------------------------------------------
// Main fused: h = x@W1 ; h = (silu if l==0) * g2 ; out = h@W2
// Block: 64 node-rows, 4 waves x 16 rows.
// ---------------------------------------------------------------------------
__global__ __launch_bounds__(256, 2) void main_k(
    const float* __restrict__ x, const f16* __restrict__ g2,
    const f16* __restrict__ W1T, const f16* __restrict__ W2T,
    float* __restrict__ out)
{
    const int t  = threadIdx.x;
    const int wv = t >> 6, ln = t & 63;
    const int col0 = ln & 15;
    const int kq   = ln >> 4;
    const int r0   = blockIdx.x * 64;

    __shared__ __align__(16) char smem[32768 + 33792];
    f16 (*xl)[136]  = (f16(*)[136])smem;       // x tile (region shared with gld)
    f16 (*gld)[256] = (f16(*)[256])smem;       // gate tile (after x consumed)
    f16 (*hld)[264] = (f16(*)[264])(smem + 32768);

    // stage x: 64 rows x 128, f32 -> f16
    #pragma unroll
    for (int it = 0; it < 4; ++it) {
        int idx = t + 256 * it;              // 1024 chunks of 8
        int row = idx >> 4, sg = idx & 15;
        int gr = r0 + row;
        f16x8 v = zero8();
        if (gr < TOTROWS) {
            const float* src = x + (size_t)gr * 128 + sg * 8;
            float4 f0 = *(const float4*)(src);
            float4 f1 = *(const float4*)(src + 4);
            v[0] = (f16)f0.x; v[1] = (f16)f0.y; v[2] = (f16)f0.z; v[3] = (f16)f0.w;
            v[4] = (f16)f1.x; v[5] = (f16)f1.y; v[6] = (f16)f1.z; v[7] = (f16)f1.w;
        }
        *(f16x8*)&xl[row][sg * 8] = v;
    }
    __syncthreads();

    f32x4 acc[16];
    #pragma unroll
    for (int nt = 0; nt < 16; ++nt) { f32x4 z = {0,0,0,0}; acc[nt] = z; }
    #pragma unroll
    for (int ks = 0; ks < 4; ++ks) {
        f16x8 a = *(const f16x8*)&xl[wv * 16 + col0][ks * 32 + kq * 8];
        #pragma unroll
        for (int nt = 0; nt < 16; ++nt) {
            f16x8 b = *(const f16x8*)(W1T + (size_t)(nt * 16 + col0) * 128 + ks * 32 + kq * 8);
            acc[nt] = __builtin_amdgcn_mfma_f32_16x16x32_f16(a, b, acc[nt], 0, 0, 0);
        }
    }
    __syncthreads();   // xl consumed; stage gate rows into same region

    #pragma unroll
    for (int it = 0; it < 8; ++it) {
        int idx = t + 256 * it;              // 2048 chunks of 8
        int row = idx >> 5, sg = idx & 31;
        int gr = r0 + row;
        f16x8 v = zero8();
        if (gr < TOTROWS) {
            int node = gr / 9, p = gr % 9;
            int l = (p > 0) + (p > 3);
            v = *(const f16x8*)(g2 + ((size_t)l * NNODES + node) * 256 + sg * 8);
        }
        *(f16x8*)&gld[row][sg * 8] = v;
    }
    __syncthreads();

    // gating -> h f16 (wave-local rows)
    #pragma unroll
    for (int nt = 0; nt < 16; ++nt)
        #pragma unroll
        for (int j = 0; j < 4; ++j) {
            int rl = wv * 16 + kq * 4 + j;
            int gr = r0 + rl;
            int p = gr % 9;
            int l = (p > 0) + (p > 3);
            float h = acc[nt][j];
            if (l == 0) h = silu(h);
            float gv = (float)gld[rl][nt * 16 + col0];
            hld[rl][nt * 16 + col0] = (f16)(h * gv);
        }

    // out = h @ W2
    f32x4 acc2[8];
    #pragma unroll
    for (int nt = 0; nt < 8; ++nt) { f32x4 z = {0,0,0,0}; acc2[nt] = z; }
    #pragma unroll
    for (int ks = 0; ks < 8; ++ks) {
        f16x8 a = *(const f16x8*)&hld[wv * 16 + col0][ks * 32 + kq * 8];
        #pragma unroll
        for (int nt = 0; nt < 8; ++nt) {
            f16x8 b = *(const f16x8*)(W2T + (size_t)(nt * 16 + col0) * 256 + ks * 32 + kq * 8);
            acc2[nt] = __builtin_amdgcn_mfma_f32_16x16x32_f16(a, b, acc2[nt], 0, 0, 0);
        }
    }
    #pragma unroll
    for (int nt = 0; nt < 8; ++nt)
        #pragma unroll
        for (int j = 0; j < 4; ++j) {
            int rl = wv * 16 + kq * 4 + j;
            int gr = r0 + rl;
            if (gr < TOTROWS) out[(size_t)gr * 128 + nt * 16 + col0] = acc2[nt][j];
        }
}

// ---------------------------------------------------------------------------
extern "C" void kernel_launch(void* const* d_in, const int* in_sizes, int n_in,
                              void* d_out, int out_size, void* d_ws, size_t ws_size,
                              hipStream_t stream) {
    const float* x_emb = (const float*)d_in[0];
    const float* t_ij  = (const float*)d_in[1];
    const float* a_ij  = (const float*)d_in[2];
    const int*   eidx  = (const int*)d_in[3];
    const float* W1  = (const float*)d_in[4];
    const float* W2  = (const float*)d_in[5];
    const float* Wg1 = (const float*)d_in[6];
    const float* bg1 = (const float*)d_in[7];
    const float* Wg2 = (const float*)d_in[8];
    const float* bg2 = (const float*)d_in[9];
    float* out = (float*)d_out;
    const int* dst = eidx + NEDGES;

    // workspace layout
    char* p = (char*)d_ws;
    int* cnt       = (int*)p;                 p += (size_t)NNODES * 4;
    int* cur       = (int*)p;                 p += (size_t)NNODES * 4;
    int* row_start = (int*)p;                 p += (size_t)(NNODES + 16) * 4;
    int* eids      = (int*)p;                 p += (size_t)NEDGES * 4;
    f16* base      = (f16*)p;                 p += (size_t)NNODES * 384 * 2;
    f16* norms     = (f16*)p;                 p += (size_t)3 * NNODES * 128 * 2;
    f16* g2b       = (f16*)p;                 p += (size_t)3 * NNODES * 256 * 2;
    f16* W1T       = (f16*)p;                 p += (size_t)32768 * 2;
    f16* W2T       = (f16*)p;                 p += (size_t)32768 * 2;
    f16* Wg1T      = (f16*)p;                 p += (size_t)393216 * 2;
    f16* Wg2T      = (f16*)p;                 p += (size_t)196608 * 2;

    hipMemsetAsync(cnt, 0, (size_t)2 * NNODES * 4, stream);  // cnt + cur

    wprep_k<<<1536, 256, 0, stream>>>(W1, W2, Wg1, Wg2, W1T, W2T, Wg1T, Wg2T);
    prep_k<<<NNODES / 2, 256, 0, stream>>>(x_emb, base, norms);
    hist_k<<<NEDGES / 256, 256, 0, stream>>>(dst, cnt);
    scan_k<<<1, 1024, 0, stream>>>(cnt, row_start);
    fill_k<<<NEDGES / 256, 256, 0, stream>>>(dst, row_start, cur, eids);
    gather_k<<<NNODES / 4, 256, 0, stream>>>(t_ij, a_ij, row_start, cnt, eids, base);
    dim3 gg((NNODES + 63) / 64, 3);
    gate_k<<<gg, 256, 0, stream>>>(base, norms, Wg1T, Wg2T, bg1, bg2, g2b);
    main_k<<<(TOTROWS + 63) / 64, 256, 0, stream>>>(x_emb, g2b, W1T, W2T, out);
}